// Round 7
// baseline (11399.001 us; speedup 1.0000x reference)
//
#include <hip/hip_runtime.h>
#include <hip/hip_bf16.h>

#define EPSF 1e-15f

typedef __hip_bfloat16 bf16;
typedef __attribute__((ext_vector_type(8))) short short8;
typedef __attribute__((ext_vector_type(4))) float f32x4;

#define F4E(v,i) ((i)==0?(v).x:((i)==1?(v).y:((i)==2?(v).z:(v).w)))
#define U4E(v,i) ((i)==0?(v).x:((i)==1?(v).y:((i)==2?(v).z:(v).w)))

// ---------- helpers ----------
__device__ __forceinline__ float artanh_c(float x) {
  x = fminf(fmaxf(x, -1.f + 1e-5f), 1.f - 1e-5f);
  return 0.5f * log1pf(2.f * x / (1.f - x));
}
__device__ __forceinline__ float sigmoidf(float x) { return 1.f / (1.f + expf(-x)); }
__device__ __forceinline__ float wave_sum(float x) {
#pragma unroll
  for (int o = 32; o > 0; o >>= 1) x += __shfl_xor(x, o);
  return x;
}
__device__ __forceinline__ float bu2f(ushort u) { return __uint_as_float(((unsigned)u) << 16); }
__device__ __forceinline__ ushort f2bu(float v) {
  bf16 t = __float2bfloat16(v);
  union { bf16 b; ushort u; } c; c.b = t; return c.u;
}
__device__ __forceinline__ void split2(float v, ushort& h, ushort& l) {
  h = f2bu(v); l = f2bu(v - bu2f(h));
}

// ---------- weight packing: fragment-major bf16 (hi plane only; once per call) ----------
// W0 per GRU (917504): h-part (cols 0-1023 = Whz|Whr, K=512) then x-part
// (cols 0-1535 = Uxz|Uxr|Uxh, K=256). Packed unit = (col-tile, ki): 64 lanes x 8 shorts,
// lane l covers col=ct*16+(l&15), k=ki*32+(l>>4)*8.. -> wave B-frag load = 1KB coalesced.
__global__ __launch_bounds__(256) void k_wconv(
    const float* __restrict__ w_ih_src, const float* __restrict__ w_hh_src,
    const float* __restrict__ w_ih_tgt, const float* __restrict__ w_hh_tgt,
    bf16* __restrict__ W0h, bf16* __restrict__ W1h)
{
  const int idx = blockIdx.x * 256 + threadIdx.x;   // 2359296 total
  float v;
  if (idx < 1835008) {
    const int g = idx / 917504, p = idx % 917504;
    const float* wih = g ? w_ih_tgt : w_ih_src;
    const float* whh = g ? w_hh_tgt : w_hh_src;
    if (p < 524288) {                 // h-part, K=512
      const int unit = p >> 9, r = p & 511, lane = r >> 3, e = r & 7;
      const int ct = unit >> 4, ki = unit & 15;
      const int col = ct*16 + (lane & 15), k = ki*32 + (lane >> 4)*8 + e;
      v = (col < 512) ? whh[524288 + col*512 + k]      // Whz = w_hh[2]
                      : whh[(col - 512)*512 + k];      // Whr = w_hh[0]
    } else {                          // x-part, K=256
      const int q = p - 524288;
      const int unit = q >> 9, r = q & 511, lane = r >> 3, e = r & 7;
      const int ct = unit >> 3, ki = unit & 7;
      const int col = ct*16 + (lane & 15), k = ki*32 + (lane >> 4)*8 + e;
      v = (col < 512)  ? wih[262144 + col*256 + k]           // Uxz = w_ih[2]
        : (col < 1024) ? wih[(col - 512)*256 + k]            // Uxr = w_ih[0]
                       : wih[131072 + (col - 1024)*256 + k]; // Uxh = w_ih[1]
    }
    ((ushort*)W0h)[idx] = f2bu(v);
  } else {
    const int j = idx - 1835008;
    if (j >= 524288) return;
    const int g = j >> 18, p = j & 262143;
    const float* whh = g ? w_hh_tgt : w_hh_src;
    const int unit = p >> 9, r = p & 511, lane = r >> 3, e = r & 7;
    const int ct = unit >> 4, ki = unit & 15;
    const int col = ct*16 + (lane & 15), k = ki*32 + (lane >> 4)*8 + e;
    v = whh[262144 + col*512 + k];                     // W_hh_ = w_hh[1]
    ((ushort*)W1h)[j] = f2bu(v);
  }
}

// ---------- row-local gate math (pure registers; verified rounds 2-6) ----------
__device__ __forceinline__ void gate_row(
    const float h[8], const float whz[8], const float whr[8],
    const float uxz[8], const float uxr[8], const float uxh[8],
    const float bz[8], const float br[8],
    float xn_x, float axn_x,
    float rh[8], float pz[8], float puhx[8],
    float& o_xnrh, float& o_axnrh, float& o_y2u, float& o_sh2)
{
  float r60=0, r61=0, r62=0, r63=0, r64_=0, r65=0;
#pragma unroll
  for (int e = 0; e < 8; e++) {
    r60 += h[e]*h[e];     r61 += whz[e]*whz[e]; r62 += whr[e]*whr[e];
    r63 += uxz[e]*uxz[e]; r64_ += uxr[e]*uxr[e]; r65 += uxh[e]*uxh[e];
  }
  r60 = wave_sum(r60); r61 = wave_sum(r61); r62 = wave_sum(r62);
  r63 = wave_sum(r63); r64_ = wave_sum(r64_); r65 = wave_sum(r65);
  const float sh2 = r60;
  const float xn_h = sqrtf(fmaxf(sh2, EPSF)), axn_h = artanh_c(xn_h);
  const float mz = sqrtf(fmaxf(r61, EPSF)); const float tz = tanhf(mz / xn_h * axn_h);
  const float sz = (mz <= 1e-7f) ? 0.f : tz/mz; const float x2z = (mz <= 1e-7f) ? 0.f : tz*tz;
  const float mr = sqrtf(fmaxf(r62, EPSF)); const float tr_ = tanhf(mr / xn_h * axn_h);
  const float sr = (mr <= 1e-7f) ? 0.f : tr_/mr; const float x2r = (mr <= 1e-7f) ? 0.f : tr_*tr_;
  const float muz = sqrtf(fmaxf(r63, EPSF)); const float tuz = tanhf(muz / xn_x * axn_x);
  const float suz = (muz <= 1e-7f) ? 0.f : tuz/muz; const float y2z = (muz <= 1e-7f) ? 0.f : tuz*tuz;
  const float mur = sqrtf(fmaxf(r64_, EPSF)); const float tur = tanhf(mur / xn_x * axn_x);
  const float sur = (mur <= 1e-7f) ? 0.f : tur/mur; const float y2r = (mur <= 1e-7f) ? 0.f : tur*tur;
  const float muh = sqrtf(fmaxf(r65, EPSF)); const float tuh = tanhf(muh / xn_x * axn_x);
  const float suh = (muh <= 1e-7f) ? 0.f : tuh/muh; const float y2u = (muh <= 1e-7f) ? 0.f : tuh*tuh;

  float dd0 = 0, dd1 = 0;
#pragma unroll
  for (int e = 0; e < 8; e++) {
    dd0 += (sz*whz[e])*(suz*uxz[e]);
    dd1 += (sr*whr[e])*(sur*uxr[e]);
  }
  dd0 = wave_sum(dd0); dd1 = wave_sum(dd1);
  float t1z[8], t1r[8];
  {
    const float iv = 1.f / fmaxf(1.f + 2.f*dd0 + x2z*y2z, EPSF);
    const float c1 = 1.f + 2.f*dd0 + y2z, c2 = 1.f - x2z;
#pragma unroll
    for (int e = 0; e < 8; e++) t1z[e] = (c1*(sz*whz[e]) + c2*(suz*uxz[e])) * iv;
  }
  {
    const float iv = 1.f / fmaxf(1.f + 2.f*dd1 + x2r*y2r, EPSF);
    const float c1 = 1.f + 2.f*dd1 + y2r, c2 = 1.f - x2r;
#pragma unroll
    for (int e = 0; e < 8; e++) t1r[e] = (c1*(sr*whr[e]) + c2*(sur*uxr[e])) * iv;
  }
  float e0=0, e1=0, e2=0, e3=0, e4=0, e5=0;
#pragma unroll
  for (int e = 0; e < 8; e++) {
    e0 += t1z[e]*t1z[e]; e1 += t1z[e]*bz[e]; e2 += bz[e]*bz[e];
    e3 += t1r[e]*t1r[e]; e4 += t1r[e]*br[e]; e5 += br[e]*br[e];
  }
  e0 = wave_sum(e0); e1 = wave_sum(e1); e2 = wave_sum(e2);
  e3 = wave_sum(e3); e4 = wave_sum(e4); e5 = wave_sum(e5);
  float t2z[8], t2r[8];
  {
    const float iv = 1.f / fmaxf(1.f + 2.f*e1 + e0*e2, EPSF);
    const float c1 = 1.f + 2.f*e1 + e2, c2 = 1.f - e0;
#pragma unroll
    for (int e = 0; e < 8; e++) t2z[e] = (c1*t1z[e] + c2*bz[e]) * iv;
  }
  {
    const float iv = 1.f / fmaxf(1.f + 2.f*e4 + e3*e5, EPSF);
    const float c1 = 1.f + 2.f*e4 + e5, c2 = 1.f - e3;
#pragma unroll
    for (int e = 0; e < 8; e++) t2r[e] = (c1*t1r[e] + c2*br[e]) * iv;
  }
  float n0 = 0, n1 = 0;
#pragma unroll
  for (int e = 0; e < 8; e++) { n0 += t2z[e]*t2z[e]; n1 += t2r[e]*t2r[e]; }
  n0 = wave_sum(n0); n1 = wave_sum(n1);
  const float nz = sqrtf(fmaxf(n0, EPSF)); const float fz = artanh_c(nz) / nz;
  const float nr = sqrtf(fmaxf(n1, EPSF)); const float frg = artanh_c(nr) / nr;
  float wx[8];
  float rw = 0;
#pragma unroll
  for (int e = 0; e < 8; e++) {
    pz[e] = sigmoidf(fz * t2z[e]);
    const float rr = sigmoidf(frg * t2r[e]);
    wx[e] = rr * h[e];
    rw += wx[e]*wx[e];
  }
  rw = wave_sum(rw);
  const float wxn = sqrtf(fmaxf(rw, EPSF));
  const float trh = tanhf(wxn / xn_h * axn_h);
  const float srh = (wxn <= 1e-7f) ? 0.f : trh / wxn;
  const float xn_rh = (wxn <= 1e-7f) ? sqrtf(EPSF) : fmaxf(trh, sqrtf(EPSF));
#pragma unroll
  for (int e = 0; e < 8; e++) { rh[e] = srh * wx[e]; puhx[e] = suh * uxh[e]; }
  o_xnrh = xn_rh; o_axnrh = artanh_c(xn_rh); o_y2u = y2u; o_sh2 = sh2;
}

// ---------- row-local update math ----------
__device__ __forceinline__ void update_row(
    const float mt_[8], const float bh[8],
    const float pz[8], const float puhx[8], const float phv[8],
    float p_xnrh, float p_axnrh, float p_y2u, float p_sh2,
    float hnew[8])
{
  float a0s = 0, a1s = 0;
#pragma unroll
  for (int e = 0; e < 8; e++) { a0s += mt_[e]*mt_[e]; a1s += mt_[e]*puhx[e]; }
  a0s = wave_sum(a0s); a1s = wave_sum(a1s);
  const float m = sqrtf(fmaxf(a0s, EPSF));
  const float tt = tanhf(m / p_xnrh * p_axnrh);
  const float st = (m <= 1e-7f) ? 0.f : tt/m;
  const float x2 = (m <= 1e-7f) ? 0.f : tt*tt;
  float t1[8];
  {
    const float xy = st * a1s;
    const float iv = 1.f / fmaxf(1.f + 2.f*xy + x2*p_y2u, EPSF);
    const float c1 = 1.f + 2.f*xy + p_y2u, c2 = 1.f - x2;
#pragma unroll
    for (int e = 0; e < 8; e++) t1[e] = (c1*(st*mt_[e]) + c2*puhx[e]) * iv;
  }
  float b0s = 0, b1s = 0, b2s = 0;
#pragma unroll
  for (int e = 0; e < 8; e++) { b0s += t1[e]*t1[e]; b1s += t1[e]*bh[e]; b2s += bh[e]*bh[e]; }
  b0s = wave_sum(b0s); b1s = wave_sum(b1s); b2s = wave_sum(b2s);
  float ht[8];
  {
    const float iv = 1.f / fmaxf(1.f + 2.f*b1s + b0s*b2s, EPSF);
    const float c1 = 1.f + 2.f*b1s + b2s, c2 = 1.f - b0s;
#pragma unroll
    for (int e = 0; e < 8; e++) ht[e] = (c1*t1[e] + c2*bh[e]) * iv;
  }
  float c0s = 0, c1s = 0;
#pragma unroll
  for (int e = 0; e < 8; e++) { c0s += ht[e]*ht[e]; c1s += phv[e]*ht[e]; }
  c0s = wave_sum(c0s); c1s = wave_sum(c1s);
  float delta[8];
  {
    const float xy = -c1s;
    const float iv = 1.f / fmaxf(1.f + 2.f*xy + p_sh2*c0s, EPSF);
    const float c1 = 1.f + 2.f*xy + c0s, c2 = 1.f - p_sh2;
#pragma unroll
    for (int e = 0; e < 8; e++) delta[e] = (c1*(-phv[e]) + c2*ht[e]) * iv;
  }
  float d0s = 0, d1s = 0, d2s = 0;
#pragma unroll
  for (int e = 0; e < 8; e++) {
    const float ww = pz[e]*delta[e];
    d0s += delta[e]*delta[e]; d1s += ww*ww; d2s += phv[e]*ww;
  }
  d0s = wave_sum(d0s); d1s = wave_sum(d1s); d2s = wave_sum(d2s);
  const float dn = sqrtf(fmaxf(d0s, EPSF));
  const float axnd = artanh_c(dn);
  const float wxn = sqrtf(fmaxf(d1s, EPSF));
  const float tzd = tanhf(wxn / dn * axnd);
  const float szd = (wxn <= 1e-7f) ? 0.f : tzd/wxn;
  const float y2zd = (wxn <= 1e-7f) ? 0.f : tzd*tzd;
  const float xy = szd * d2s;
  const float iv = 1.f / fmaxf(1.f + 2.f*xy + p_sh2*y2zd, EPSF);
  const float c1 = 1.f + 2.f*xy + y2zd, c2 = 1.f - p_sh2;
#pragma unroll
  for (int e = 0; e < 8; e++) hnew[e] = (c1*phv[e] + c2*(szd*pz[e]*delta[e])) * iv;
}

// ---------- the row-local persistent RNN kernel: 64 blocks x 16 rows ----------
// r7 changes vs r6: (1) y stored bf16 (per-XCD L2 footprint 3.9->3.25MB => weights
// L2-resident); (2) manual double-buffered weight prefetch in ph1a/ph3 (~8KB in
// flight/wave continuously -> covers L2/HBM latency).
// LDS map (64KB): [0,16K)=H_hi [16K,32K)=H_lo; ph1 x_hi@32K x_lo@40K;
// ph2-3 rh_hi@32K rh_lo@48K. XOR swizzle byte^=((row&7)<<4) on all act planes.
__global__ __launch_bounds__(512, 1) void k_rnn(
    const float* __restrict__ emb, const int* __restrict__ src_t,
    const int* __restrict__ tgt_t, const float* __restrict__ b_src,
    const float* __restrict__ b_tgt,
    const bf16* __restrict__ W0h_, const bf16* __restrict__ W1h_,
    ushort* __restrict__ yws, float* __restrict__ htmws,
    float* __restrict__ hbuf)
{
  const int bid = blockIdx.x, tid = threadIdx.x;
  const int w = tid >> 6, lane = tid & 63;
  const int fr = lane & 15, kg = lane >> 4;
  const int xcd = bid & 7, slot = bid >> 3;
  const int g = xcd >> 2;                    // XCDs 0-3 -> GRU0, 4-7 -> GRU1
  const int b16 = (xcd & 3) * 8 + slot;      // 0..31 within GRU
  const bf16* W0h = W0h_ + (size_t)g * 917504;
  const bf16* W1h = W1h_ + (size_t)g * 262144;
  const int* toks = g ? tgt_t : src_t;
  const float* bb = g ? b_tgt : b_src;
  ushort* yslu = yws + (size_t)bid * 40960;  // [16][2560] bf16, block-private
  float* hsl = htmws + (size_t)bid * 8192;   // [16][512]  f32, block-private

  __shared__ char L[65536];
  for (int i = tid; i < 2048; i += 512) ((float4*)L)[i] = make_float4(0.f,0.f,0.f,0.f);

  float p_xnx[2], p_axnx[2];
  float pz_[2][8], puhx_[2][8], phh_[2][8];
  float p_xnrh[2], p_axnrh[2], p_y2u[2], p_sh2[2];

#define XLOAD(RI, TOKIDX)                                                        \
  {                                                                              \
    const int row = w*2 + (RI);                                                  \
    const int tok = toks[(b16*16 + row)*100 + (TOKIDX)];                         \
    const float4 ev = ((const float4*)(emb + (size_t)tok * 256))[lane];          \
    float ss = ev.x*ev.x + ev.y*ev.y + ev.z*ev.z + ev.w*ev.w;                    \
    ss = wave_sum(ss);                                                           \
    const float un = sqrtf(fmaxf(ss, EPSF));                                     \
    const float fac = tanhf(un) / un;                                            \
    const float xnv = sqrtf(fmaxf(fac*fac*ss, EPSF));                            \
    p_xnx[RI] = xnv; p_axnx[RI] = artanh_c(xnv);                                 \
    ushort th[4], tl[4];                                                         \
    split2(fac*ev.x, th[0], tl[0]); split2(fac*ev.y, th[1], tl[1]);              \
    split2(fac*ev.z, th[2], tl[2]); split2(fac*ev.w, th[3], tl[3]);              \
    const unsigned xo = (unsigned)((row*512 + lane*8) ^ ((row & 7) << 4));       \
    *(ushort4*)(L + 32768 + xo) = make_ushort4(th[0],th[1],th[2],th[3]);         \
    *(ushort4*)(L + 40960 + xo) = make_ushort4(tl[0],tl[1],tl[2],tl[3]);         \
  }

  XLOAD(0, 0)
  XLOAD(1, 0)
  __syncthreads();

  for (int s = 0; s < 100; s++) {
    // ===== phase 1a: y[:, 0:1024] = H @ {Whz|Whr}^T (K=512, 8 tiles/wave) =====
    // manual 2-stage weight prefetch: bA holds ki, bB holds ki+1.
    {
      const f32x4 z4 = {0.f,0.f,0.f,0.f};
      f32x4 acc[8];
#pragma unroll
      for (int t = 0; t < 8; t++) acc[t] = z4;
      short8 bA[8], bB[8];
#pragma unroll
      for (int t = 0; t < 8; t++)
        bA[t] = *(const short8*)(W0h + (size_t)(((w*8 + t)*16 + 0)*512) + lane*8);
      for (int ki2 = 0; ki2 < 8; ki2++) {
        const int kiE = ki2*2, kiO = kiE + 1;
#pragma unroll
        for (int t = 0; t < 8; t++)
          bB[t] = *(const short8*)(W0h + (size_t)(((w*8 + t)*16 + kiO)*512) + lane*8);
        {
          const unsigned ao = (unsigned)((fr*1024 + kiE*64 + kg*16) ^ ((fr & 7) << 4));
          const short8 aHi = *(const short8*)(L + ao);
          const short8 aLo = *(const short8*)(L + 16384 + ao);
#pragma unroll
          for (int t = 0; t < 8; t++) {
            acc[t] = __builtin_amdgcn_mfma_f32_16x16x32_bf16(aHi, bA[t], acc[t], 0,0,0);
            acc[t] = __builtin_amdgcn_mfma_f32_16x16x32_bf16(aLo, bA[t], acc[t], 0,0,0);
          }
        }
        if (ki2 < 7) {
#pragma unroll
          for (int t = 0; t < 8; t++)
            bA[t] = *(const short8*)(W0h + (size_t)(((w*8 + t)*16 + kiE + 2)*512) + lane*8);
        }
        {
          const unsigned ao = (unsigned)((fr*1024 + kiO*64 + kg*16) ^ ((fr & 7) << 4));
          const short8 aHi = *(const short8*)(L + ao);
          const short8 aLo = *(const short8*)(L + 16384 + ao);
#pragma unroll
          for (int t = 0; t < 8; t++) {
            acc[t] = __builtin_amdgcn_mfma_f32_16x16x32_bf16(aHi, bB[t], acc[t], 0,0,0);
            acc[t] = __builtin_amdgcn_mfma_f32_16x16x32_bf16(aLo, bB[t], acc[t], 0,0,0);
          }
        }
      }
#pragma unroll
      for (int t = 0; t < 8; t++) {
        const int colb = (w*8 + t)*16 + fr;
#pragma unroll
        for (int r = 0; r < 4; r++)
          yslu[(size_t)(kg*4 + r)*2560 + colb] = f2bu(acc[t][r]);
      }
    }
    // ===== phase 1b: y[:, 1024:2560] = X @ {Uxz|Uxr|Uxh}^T (K=256, 12 tiles/wave) =====
    {
      const f32x4 z4 = {0.f,0.f,0.f,0.f};
      f32x4 acc[12];
#pragma unroll
      for (int t = 0; t < 12; t++) acc[t] = z4;
      for (int ki = 0; ki < 8; ki++) {
        short8 bfr[12];
#pragma unroll
        for (int t = 0; t < 12; t++)
          bfr[t] = *(const short8*)(W0h + 524288 + (size_t)(((w*12 + t)*8 + ki)*512) + lane*8);
        const unsigned ao = (unsigned)((fr*512 + ki*64 + kg*16) ^ ((fr & 7) << 4));
        const short8 aHi = *(const short8*)(L + 32768 + ao);
        const short8 aLo = *(const short8*)(L + 40960 + ao);
#pragma unroll
        for (int t = 0; t < 12; t++) {
          acc[t] = __builtin_amdgcn_mfma_f32_16x16x32_bf16(aHi, bfr[t], acc[t], 0,0,0);
          acc[t] = __builtin_amdgcn_mfma_f32_16x16x32_bf16(aLo, bfr[t], acc[t], 0,0,0);
        }
      }
#pragma unroll
      for (int t = 0; t < 12; t++) {
        const int colb = 1024 + (w*12 + t)*16 + fr;
#pragma unroll
        for (int r = 0; r < 4; r++)
          yslu[(size_t)(kg*4 + r)*2560 + colb] = f2bu(acc[t][r]);
      }
    }
    __syncthreads();

    // ===== phase 2: gates, wave handles rows w*2, w*2+1 =====
#define PH2_ROW(RI)                                                              \
    {                                                                            \
      const int row = w*2 + (RI);                                                \
      const ushort* growu = yslu + row * 2560;                                   \
      float h[8], whz[8], whr[8], uxz[8], uxr[8], uxh[8], bz[8], br[8];          \
      _Pragma("unroll")                                                          \
      for (int q = 0; q < 2; q++) {                                              \
        const int j4 = lane + 64*q;                                              \
        const unsigned ho = (unsigned)((row*1024 + j4*8) ^ ((row & 7) << 4));    \
        const ushort4 hh4 = *(const ushort4*)(L + ho);                           \
        const ushort4 hl4 = *(const ushort4*)(L + 16384 + ho);                   \
        const ushort4 vz  = ((const ushort4*)growu)[j4];                         \
        const ushort4 vr  = ((const ushort4*)(growu + 512))[j4];                 \
        const ushort4 uz  = ((const ushort4*)(growu + 1024))[j4];                \
        const ushort4 ur  = ((const ushort4*)(growu + 1536))[j4];                \
        const ushort4 uh  = ((const ushort4*)(growu + 2048))[j4];                \
        const float4 vbz = ((const float4*)(bb + 1024))[j4];                     \
        const float4 vbr = ((const float4*)bb)[j4];                              \
        _Pragma("unroll")                                                        \
        for (int i = 0; i < 4; i++) {                                            \
          const int e = q*4 + i;                                                 \
          h[e] = bu2f(U4E(hh4,i)) + bu2f(U4E(hl4,i));                            \
          whz[e] = bu2f(U4E(vz,i)); whr[e] = bu2f(U4E(vr,i));                    \
          uxz[e] = bu2f(U4E(uz,i)); uxr[e] = bu2f(U4E(ur,i));                    \
          uxh[e] = bu2f(U4E(uh,i));                                              \
          bz[e] = F4E(vbz,i); br[e] = F4E(vbr,i);                               \
        }                                                                        \
      }                                                                          \
      float rh[8];                                                               \
      gate_row(h, whz, whr, uxz, uxr, uxh, bz, br, p_xnx[RI], p_axnx[RI],        \
               rh, pz_[RI], puhx_[RI],                                           \
               p_xnrh[RI], p_axnrh[RI], p_y2u[RI], p_sh2[RI]);                   \
      _Pragma("unroll")                                                          \
      for (int e = 0; e < 8; e++) phh_[RI][e] = h[e];                            \
      _Pragma("unroll")                                                          \
      for (int q = 0; q < 2; q++) {                                              \
        const int j4 = lane + 64*q;                                              \
        const unsigned ro = (unsigned)((row*1024 + j4*8) ^ ((row & 7) << 4));    \
        ushort th[4], tl[4];                                                     \
        _Pragma("unroll")                                                        \
        for (int i = 0; i < 4; i++) split2(rh[q*4+i], th[i], tl[i]);             \
        *(ushort4*)(L + 32768 + ro) = make_ushort4(th[0],th[1],th[2],th[3]);     \
        *(ushort4*)(L + 49152 + ro) = make_ushort4(tl[0],tl[1],tl[2],tl[3]);     \
      }                                                                          \
    }

    PH2_ROW(0)
    PH2_ROW(1)
    __syncthreads();

    // ===== phase 3: htm = RH @ W1^T (K=512, 4 tiles/wave, 2-stage prefetch) =====
    {
      const f32x4 z4 = {0.f,0.f,0.f,0.f};
      f32x4 acc[4];
#pragma unroll
      for (int t = 0; t < 4; t++) acc[t] = z4;
      short8 bA[4], bB[4];
#pragma unroll
      for (int t = 0; t < 4; t++)
        bA[t] = *(const short8*)(W1h + (size_t)(((w*4 + t)*16 + 0)*512) + lane*8);
      for (int ki2 = 0; ki2 < 8; ki2++) {
        const int kiE = ki2*2, kiO = kiE + 1;
#pragma unroll
        for (int t = 0; t < 4; t++)
          bB[t] = *(const short8*)(W1h + (size_t)(((w*4 + t)*16 + kiO)*512) + lane*8);
        {
          const unsigned ao = (unsigned)((fr*1024 + kiE*64 + kg*16) ^ ((fr & 7) << 4));
          const short8 aHi = *(const short8*)(L + 32768 + ao);
          const short8 aLo = *(const short8*)(L + 49152 + ao);
#pragma unroll
          for (int t = 0; t < 4; t++) {
            acc[t] = __builtin_amdgcn_mfma_f32_16x16x32_bf16(aHi, bA[t], acc[t], 0,0,0);
            acc[t] = __builtin_amdgcn_mfma_f32_16x16x32_bf16(aLo, bA[t], acc[t], 0,0,0);
          }
        }
        if (ki2 < 7) {
#pragma unroll
          for (int t = 0; t < 4; t++)
            bA[t] = *(const short8*)(W1h + (size_t)(((w*4 + t)*16 + kiE + 2)*512) + lane*8);
        }
        {
          const unsigned ao = (unsigned)((fr*1024 + kiO*64 + kg*16) ^ ((fr & 7) << 4));
          const short8 aHi = *(const short8*)(L + 32768 + ao);
          const short8 aLo = *(const short8*)(L + 49152 + ao);
#pragma unroll
          for (int t = 0; t < 4; t++) {
            acc[t] = __builtin_amdgcn_mfma_f32_16x16x32_bf16(aHi, bB[t], acc[t], 0,0,0);
            acc[t] = __builtin_amdgcn_mfma_f32_16x16x32_bf16(aLo, bB[t], acc[t], 0,0,0);
          }
        }
      }
#pragma unroll
      for (int t = 0; t < 4; t++) {
        const int colb = (w*4 + t)*16 + fr;
#pragma unroll
        for (int r = 0; r < 4; r++)
          hsl[(size_t)(kg*4 + r)*512 + colb] = acc[t][r];
      }
    }
    __syncthreads();

    // ===== phase 4: update, wave handles rows w*2, w*2+1; prefetch next x =====
#define PH4_ROW(RI)                                                              \
    {                                                                            \
      const int row = w*2 + (RI);                                                \
      float mt_[8], bh[8];                                                       \
      _Pragma("unroll")                                                          \
      for (int q = 0; q < 2; q++) {                                              \
        const int j4 = lane + 64*q;                                              \
        const float4 vm = ((const float4*)(hsl + row*512))[j4];                  \
        const float4 vb = ((const float4*)(bb + 512))[j4];                       \
        _Pragma("unroll")                                                        \
        for (int i = 0; i < 4; i++) {                                            \
          mt_[q*4+i] = F4E(vm,i); bh[q*4+i] = F4E(vb,i);                         \
        }                                                                        \
      }                                                                          \
      float hnew[8];                                                             \
      update_row(mt_, bh, pz_[RI], puhx_[RI], phh_[RI],                          \
                 p_xnrh[RI], p_axnrh[RI], p_y2u[RI], p_sh2[RI], hnew);           \
      _Pragma("unroll")                                                          \
      for (int q = 0; q < 2; q++) {                                              \
        const int j4 = lane + 64*q;                                              \
        const unsigned ho = (unsigned)((row*1024 + j4*8) ^ ((row & 7) << 4));    \
        ushort th[4], tl[4];                                                     \
        _Pragma("unroll")                                                        \
        for (int i = 0; i < 4; i++) split2(hnew[q*4+i], th[i], tl[i]);           \
        *(ushort4*)(L + ho) = make_ushort4(th[0],th[1],th[2],th[3]);             \
        *(ushort4*)(L + 16384 + ho) = make_ushort4(tl[0],tl[1],tl[2],tl[3]);     \
        if (s == 99)                                                             \
          ((float4*)(hbuf + (size_t)(g*512 + b16*16 + row)*512))[j4] =           \
              make_float4(hnew[q*4], hnew[q*4+1], hnew[q*4+2], hnew[q*4+3]);     \
      }                                                                          \
      if (s + 1 < 100) XLOAD(RI, s + 1)                                          \
    }

    PH4_ROW(0)
    PH4_ROW(1)
    __syncthreads();
  }
}

// ---------- head projection GEMM (f32, runs once; verified rounds 2-6) ----------
__global__ __launch_bounds__(256) void gemm_k(
    const float* __restrict__ hbuf,
    const float* __restrict__ wp_src, const float* __restrict__ wp_tgt,
    const int* __restrict__ alignment,
    float* __restrict__ out)
{
  const int rt = blockIdx.x, ct = blockIdx.y;
  const int rowBase = rt * 64;
  const int tid = threadIdx.x;
  const int chunk = ct >> 2;
  const int colBase = ct * 64, ldo = 512, kdim = 512;
  const float* W = (chunk ? wp_tgt : wp_src) + (size_t)((ct & 3) * 64) * 512;
  const int ar = tid >> 2, ak = (tid & 3) * 4;
  int arow = rowBase + ar;
  if (chunk) arow = 512 + alignment[arow];
  const float* Arow = hbuf + (size_t)arow * kdim;
  const float* Wrow = W + (size_t)(tid >> 2) * kdim + (tid & 3) * 4;

  __shared__ __align__(16) float As[16][68];
  __shared__ __align__(16) float Bs[16][68];
  float acc[4][4] = {{0.f}};
  const int ty = tid >> 4, tx = tid & 15;

  for (int k0 = 0; k0 < kdim; k0 += 16) {
    const float4 av = *(const float4*)(Arow + k0 + ak);
    const float4 bv = *(const float4*)(Wrow + k0);
    const int bj = tid >> 2;
    As[ak + 0][ar] = av.x; As[ak + 1][ar] = av.y; As[ak + 2][ar] = av.z; As[ak + 3][ar] = av.w;
    Bs[ak + 0][bj] = bv.x; Bs[ak + 1][bj] = bv.y; Bs[ak + 2][bj] = bv.z; Bs[ak + 3][bj] = bv.w;
    __syncthreads();
#pragma unroll
    for (int kk = 0; kk < 16; kk++) {
      const float4 a4 = *(const float4*)(&As[kk][ty * 4]);
      const float4 b4 = *(const float4*)(&Bs[kk][tx * 4]);
      acc[0][0] += a4.x * b4.x; acc[0][1] += a4.x * b4.y; acc[0][2] += a4.x * b4.z; acc[0][3] += a4.x * b4.w;
      acc[1][0] += a4.y * b4.x; acc[1][1] += a4.y * b4.y; acc[1][2] += a4.y * b4.z; acc[1][3] += a4.y * b4.w;
      acc[2][0] += a4.z * b4.x; acc[2][1] += a4.z * b4.y; acc[2][2] += a4.z * b4.z; acc[2][3] += a4.z * b4.w;
      acc[3][0] += a4.w * b4.x; acc[3][1] += a4.w * b4.y; acc[3][2] += a4.w * b4.z; acc[3][3] += a4.w * b4.w;
    }
    __syncthreads();
  }
#pragma unroll
  for (int r = 0; r < 4; r++) {
    float4 o; o.x = acc[r][0]; o.y = acc[r][1]; o.z = acc[r][2]; o.w = acc[r][3];
    *(float4*)(out + (size_t)(rowBase + ty * 4 + r) * ldo + colBase + tx * 4) = o;
  }
}

// ---------- head ----------
template<int N>
__device__ __forceinline__ void block_reduce(float* v) {
  __shared__ float s[4][N];
  __syncthreads();
  const int lane = threadIdx.x & 63;
  const int wv = threadIdx.x >> 6;
#pragma unroll
  for (int n = 0; n < N; n++) {
    float x = v[n];
#pragma unroll
    for (int o = 32; o > 0; o >>= 1) x += __shfl_down(x, o);
    if (lane == 0) s[wv][n] = x;
  }
  __syncthreads();
#pragma unroll
  for (int n = 0; n < N; n++) v[n] = s[0][n] + s[1][n] + s[2][n] + s[3][n];
}

__global__ __launch_bounds__(256) void k_head(
    const float* __restrict__ hb, const float* __restrict__ mxb,
    const float* __restrict__ bp_src, const float* __restrict__ bp_tgt,
    const float* __restrict__ dist_bias, const float* __restrict__ plane_p,
    const float* __restrict__ plane_a, const int* __restrict__ alignment,
    float* __restrict__ outp)
{
  const int b = blockIdx.x;
  const int t = threadIdx.x;
  const int arow = 512 + alignment[b];
  float hs[2], htg[2];
  hs[0] = hb[(size_t)b * 512 + t];      hs[1] = hb[(size_t)b * 512 + 256 + t];
  htg[0] = hb[(size_t)arow * 512 + t];  htg[1] = hb[(size_t)arow * 512 + 256 + t];
  const float mxs = mxb[(size_t)b * 512 + t];
  const float mxt = mxb[(size_t)b * 512 + 256 + t];
  const float bps = bp_src[t], bpt = bp_tgt[t], db = dist_bias[t];
  const float pp0 = plane_p[t], pp1 = plane_p[256 + t];
  const float pa0 = plane_a[t], pa1 = plane_a[256 + t];

  float rA[5] = {0, 0, 0, 0, 0};
#pragma unroll
  for (int e = 0; e < 2; e++) {
    rA[0] += hs[e] * hs[e]; rA[1] += htg[e] * htg[e]; rA[2] += hs[e] * htg[e];
  }
  rA[3] = mxs * mxs; rA[4] = mxt * mxt;
  block_reduce<5>(rA);
  const float shs = rA[0], sht = rA[1], dot_st = rA[2];
  const float xns = sqrtf(fmaxf(shs, EPSF)), axns = artanh_c(xns);
  const float xnt = sqrtf(fmaxf(sht, EPSF)), axnt = artanh_c(xnt);
  const float ms = sqrtf(fmaxf(rA[3], EPSF)); const float ts = tanhf(ms / xns * axns);
  const float ss = (ms <= 1e-7f) ? 0.f : ts / ms; const float x2s = (ms <= 1e-7f) ? 0.f : ts * ts;
  const float mt = sqrtf(fmaxf(rA[4], EPSF)); const float tt = tanhf(mt / xnt * axnt);
  const float st = (mt <= 1e-7f) ? 0.f : tt / mt; const float x2t = (mt <= 1e-7f) ? 0.f : tt * tt;
  const float vs = ss * mxs, vt = st * mxt;

  float rB[5] = {bps * bps, vs * bps, bpt * bpt, vt * bpt, db * db};
  block_reduce<5>(rB);
  float ps, pt;
  {
    const float y2 = rB[0], xy = rB[1];
    const float iv = 1.f / fmaxf(1.f + 2.f * xy + x2s * y2, EPSF);
    ps = ((1.f + 2.f * xy + y2) * vs + (1.f - x2s) * bps) * iv;
  }
  {
    const float y2 = rB[2], xy = rB[3];
    const float iv = 1.f / fmaxf(1.f + 2.f * xy + x2t * y2, EPSF);
    pt = ((1.f + 2.f * xy + y2) * vt + (1.f - x2t) * bpt) * iv;
  }
  float rC[2] = {ps * ps, pt * pt};
  block_reduce<2>(rC);
  {
    const float n = sqrtf(fmaxf(rC[0], EPSF));
    if (n > 0.999f) ps *= 0.999f / n;
  }
  {
    const float n = sqrtf(fmaxf(rC[1], EPSF));
    if (n > 0.999f) pt *= 0.999f / n;
  }
  float df[2];
  {
    const float xy = -dot_st;
    const float iv = 1.f / fmaxf(1.f + 2.f * xy + shs * sht, EPSF);
    const float c1 = 1.f + 2.f * xy + sht, c2 = 1.f - shs;
#pragma unroll
    for (int e = 0; e < 2; e++) df[e] = (c1 * (-hs[e]) + c2 * htg[e]) * iv;
  }
  float rD[4] = {ps * ps, pt * pt, ps * pt, df[0] * df[0] + df[1] * df[1]};
  block_reduce<4>(rD);
  float pr;
  {
    const float x2 = rD[0], y2 = rD[1], xy = rD[2];
    const float iv = 1.f / fmaxf(1.f + 2.f * xy + x2 * y2, EPSF);
    pr = ((1.f + 2.f * xy + y2) * ps + (1.f - x2) * pt) * iv;
  }
  const float dn = sqrtf(fmaxf(rD[3], EPSF));
  const float dist = 2.f * artanh_c(dn);
  const float d2v = dist * dist;
  const float dbn = sqrtf(fmaxf(rB[4], EPSF));
  const float biasv = tanhf(d2v * artanh_c(dbn)) * db / dbn;

  float rE[3] = {pr * pr, biasv * biasv, pr * biasv};
  block_reduce<3>(rE);
  float pr2;
  {
    const float x2 = rE[0], y2 = rE[1], xy = rE[2];
    const float iv = 1.f / fmaxf(1.f + 2.f * xy + x2 * y2, EPSF);
    pr2 = ((1.f + 2.f * xy + y2) * pr + (1.f - x2) * biasv) * iv;
  }
  float rF[5] = {pp0 * pp0, pp0 * pr2, pp1 * pp1, pp1 * pr2, pr2 * pr2};
  block_reduce<5>(rF);
  float d0, d1;
  {
    const float x2 = rF[0], xy = -rF[1], y2 = rF[4];
    const float iv = 1.f / fmaxf(1.f + 2.f * xy + x2 * y2, EPSF);
    d0 = ((1.f + 2.f * xy + y2) * (-pp0) + (1.f - x2) * pr2) * iv;
  }
  {
    const float x2 = rF[2], xy = -rF[3], y2 = rF[4];
    const float iv = 1.f / fmaxf(1.f + 2.f * xy + x2 * y2, EPSF);
    d1 = ((1.f + 2.f * xy + y2) * (-pp1) + (1.f - x2) * pr2) * iv;
  }
  float rG[6] = {d0 * d0, d0 * pa0, pa0 * pa0, d1 * d1, d1 * pa1, pa1 * pa1};
  block_reduce<6>(rG);
  if (t == 0) {
    const float an0 = sqrtf(fmaxf(rG[2], EPSF));
    const float an1 = sqrtf(fmaxf(rG[5], EPSF));
    outp[b * 2 + 0] = asinhf(2.f * rG[1] / fmaxf((1.f - rG[0]) * an0, EPSF));
    outp[b * 2 + 1] = asinhf(2.f * rG[4] / fmaxf((1.f - rG[3]) * an1, EPSF));
  }
}

// ---------- launch ----------
extern "C" void kernel_launch(void* const* d_in, const int* in_sizes, int n_in,
                              void* d_out, int out_size, void* d_ws, size_t ws_size,
                              hipStream_t stream) {
  const float* emb       = (const float*)d_in[0];
  const float* w_ih_src  = (const float*)d_in[1];
  const float* w_hh_src  = (const float*)d_in[2];
  const float* b_src     = (const float*)d_in[3];
  const float* w_ih_tgt  = (const float*)d_in[4];
  const float* w_hh_tgt  = (const float*)d_in[5];
  const float* b_tgt     = (const float*)d_in[6];
  const float* wp_src    = (const float*)d_in[7];
  const float* bp_src    = (const float*)d_in[8];
  const float* wp_tgt    = (const float*)d_in[9];
  const float* bp_tgt    = (const float*)d_in[10];
  const float* dist_bias = (const float*)d_in[11];
  const float* plane_p   = (const float*)d_in[12];
  const float* plane_a   = (const float*)d_in[13];
  const int* src_t       = (const int*)d_in[14];
  const int* tgt_t       = (const int*)d_in[15];
  const int* alignment   = (const int*)d_in[16];
  float* outp            = (float*)d_out;

  char* wsb = (char*)d_ws;
  ushort* yws  = (ushort*)(wsb + 0);         // 64 x [16][2560] bf16 = 5.24 MB
  float* htmws = (float*)(wsb + 5242880);    // 64 x [16][512]  f32 = 2 MB
  float* hbuf  = (float*)(wsb + 7340032);    // [1024][512] f32 = 2 MB
  float* mxb   = (float*)(wsb + 9437184);    // [512][512]  f32 = 1 MB
  bf16*  W0h   = (bf16*)(wsb + 10485760);    // 1835008 bf16 = 3.67 MB
  bf16*  W1h   = (bf16*)(wsb + 14155776);    // 524288 bf16 = 1.05 MB; end ~15.2 MB

  k_wconv<<<9216, 256, 0, stream>>>(w_ih_src, w_hh_src, w_ih_tgt, w_hh_tgt,
                                    W0h, W1h);
  k_rnn<<<64, 512, 0, stream>>>(emb, src_t, tgt_t, b_src, b_tgt,
                                W0h, W1h, yws, htmws, hbuf);
  gemm_k<<<dim3(8, 8), 256, 0, stream>>>(hbuf, wp_src, wp_tgt, alignment, mxb);
  k_head<<<512, 256, 0, stream>>>(hbuf, mxb, bp_src, bp_tgt, dist_bias,
                                  plane_p, plane_a, alignment, outp);
}

// Round 8
// 9827.784 us; speedup vs baseline: 1.1599x; 1.1599x over previous
//
#include <hip/hip_runtime.h>
#include <hip/hip_bf16.h>

#define EPSF 1e-15f

typedef __hip_bfloat16 bf16;
typedef __attribute__((ext_vector_type(8))) short short8;
typedef __attribute__((ext_vector_type(4))) float f32x4;

#define F4E(v,i) ((i)==0?(v).x:((i)==1?(v).y:((i)==2?(v).z:(v).w)))
#define U4E(v,i) ((i)==0?(v).x:((i)==1?(v).y:((i)==2?(v).z:(v).w)))

// ---------- helpers ----------
__device__ __forceinline__ float artanh_c(float x) {
  x = fminf(fmaxf(x, -1.f + 1e-5f), 1.f - 1e-5f);
  return 0.5f * log1pf(2.f * x / (1.f - x));
}
__device__ __forceinline__ float sigmoidf(float x) { return 1.f / (1.f + expf(-x)); }
__device__ __forceinline__ float wave_sum(float x) {
#pragma unroll
  for (int o = 32; o > 0; o >>= 1) x += __shfl_xor(x, o);
  return x;
}
__device__ __forceinline__ float bu2f(ushort u) { return __uint_as_float(((unsigned)u) << 16); }
__device__ __forceinline__ ushort f2bu(float v) {
  bf16 t = __float2bfloat16(v);
  union { bf16 b; ushort u; } c; c.b = t; return c.u;
}
__device__ __forceinline__ void split2(float v, ushort& h, ushort& l) {
  h = f2bu(v); l = f2bu(v - bu2f(h));
}

// ---------- weight packing: fragment-major bf16 (hi plane only; once per call) ----------
__global__ __launch_bounds__(256) void k_wconv(
    const float* __restrict__ w_ih_src, const float* __restrict__ w_hh_src,
    const float* __restrict__ w_ih_tgt, const float* __restrict__ w_hh_tgt,
    bf16* __restrict__ W0h, bf16* __restrict__ W1h)
{
  const int idx = blockIdx.x * 256 + threadIdx.x;   // 2359296 total
  float v;
  if (idx < 1835008) {
    const int g = idx / 917504, p = idx % 917504;
    const float* wih = g ? w_ih_tgt : w_ih_src;
    const float* whh = g ? w_hh_tgt : w_hh_src;
    if (p < 524288) {                 // h-part, K=512
      const int unit = p >> 9, r = p & 511, lane = r >> 3, e = r & 7;
      const int ct = unit >> 4, ki = unit & 15;
      const int col = ct*16 + (lane & 15), k = ki*32 + (lane >> 4)*8 + e;
      v = (col < 512) ? whh[524288 + col*512 + k]      // Whz = w_hh[2]
                      : whh[(col - 512)*512 + k];      // Whr = w_hh[0]
    } else {                          // x-part, K=256
      const int q = p - 524288;
      const int unit = q >> 9, r = q & 511, lane = r >> 3, e = r & 7;
      const int ct = unit >> 3, ki = unit & 7;
      const int col = ct*16 + (lane & 15), k = ki*32 + (lane >> 4)*8 + e;
      v = (col < 512)  ? wih[262144 + col*256 + k]           // Uxz = w_ih[2]
        : (col < 1024) ? wih[(col - 512)*256 + k]            // Uxr = w_ih[0]
                       : wih[131072 + (col - 1024)*256 + k]; // Uxh = w_ih[1]
    }
    ((ushort*)W0h)[idx] = f2bu(v);
  } else {
    const int j = idx - 1835008;
    if (j >= 524288) return;
    const int g = j >> 18, p = j & 262143;
    const float* whh = g ? w_hh_tgt : w_hh_src;
    const int unit = p >> 9, r = p & 511, lane = r >> 3, e = r & 7;
    const int ct = unit >> 4, ki = unit & 15;
    const int col = ct*16 + (lane & 15), k = ki*32 + (lane >> 4)*8 + e;
    v = whh[262144 + col*512 + k];                     // W_hh_ = w_hh[1]
    ((ushort*)W1h)[j] = f2bu(v);
  }
}

// ---------- row-local gate math (verified rounds 2-7) ----------
__device__ __forceinline__ void gate_row(
    const float h[8], const float whz[8], const float whr[8],
    const float uxz[8], const float uxr[8], const float uxh[8],
    const float bz[8], const float br[8],
    float xn_x, float axn_x,
    float rh[8], float pz[8], float puhx[8],
    float& o_xnrh, float& o_axnrh, float& o_y2u, float& o_sh2)
{
  float r60=0, r61=0, r62=0, r63=0, r64_=0, r65=0;
#pragma unroll
  for (int e = 0; e < 8; e++) {
    r60 += h[e]*h[e];     r61 += whz[e]*whz[e]; r62 += whr[e]*whr[e];
    r63 += uxz[e]*uxz[e]; r64_ += uxr[e]*uxr[e]; r65 += uxh[e]*uxh[e];
  }
  r60 = wave_sum(r60); r61 = wave_sum(r61); r62 = wave_sum(r62);
  r63 = wave_sum(r63); r64_ = wave_sum(r64_); r65 = wave_sum(r65);
  const float sh2 = r60;
  const float xn_h = sqrtf(fmaxf(sh2, EPSF)), axn_h = artanh_c(xn_h);
  const float mz = sqrtf(fmaxf(r61, EPSF)); const float tz = tanhf(mz / xn_h * axn_h);
  const float sz = (mz <= 1e-7f) ? 0.f : tz/mz; const float x2z = (mz <= 1e-7f) ? 0.f : tz*tz;
  const float mr = sqrtf(fmaxf(r62, EPSF)); const float tr_ = tanhf(mr / xn_h * axn_h);
  const float sr = (mr <= 1e-7f) ? 0.f : tr_/mr; const float x2r = (mr <= 1e-7f) ? 0.f : tr_*tr_;
  const float muz = sqrtf(fmaxf(r63, EPSF)); const float tuz = tanhf(muz / xn_x * axn_x);
  const float suz = (muz <= 1e-7f) ? 0.f : tuz/muz; const float y2z = (muz <= 1e-7f) ? 0.f : tuz*tuz;
  const float mur = sqrtf(fmaxf(r64_, EPSF)); const float tur = tanhf(mur / xn_x * axn_x);
  const float sur = (mur <= 1e-7f) ? 0.f : tur/mur; const float y2r = (mur <= 1e-7f) ? 0.f : tur*tur;
  const float muh = sqrtf(fmaxf(r65, EPSF)); const float tuh = tanhf(muh / xn_x * axn_x);
  const float suh = (muh <= 1e-7f) ? 0.f : tuh/muh; const float y2u = (muh <= 1e-7f) ? 0.f : tuh*tuh;

  float dd0 = 0, dd1 = 0;
#pragma unroll
  for (int e = 0; e < 8; e++) {
    dd0 += (sz*whz[e])*(suz*uxz[e]);
    dd1 += (sr*whr[e])*(sur*uxr[e]);
  }
  dd0 = wave_sum(dd0); dd1 = wave_sum(dd1);
  float t1z[8], t1r[8];
  {
    const float iv = 1.f / fmaxf(1.f + 2.f*dd0 + x2z*y2z, EPSF);
    const float c1 = 1.f + 2.f*dd0 + y2z, c2 = 1.f - x2z;
#pragma unroll
    for (int e = 0; e < 8; e++) t1z[e] = (c1*(sz*whz[e]) + c2*(suz*uxz[e])) * iv;
  }
  {
    const float iv = 1.f / fmaxf(1.f + 2.f*dd1 + x2r*y2r, EPSF);
    const float c1 = 1.f + 2.f*dd1 + y2r, c2 = 1.f - x2r;
#pragma unroll
    for (int e = 0; e < 8; e++) t1r[e] = (c1*(sr*whr[e]) + c2*(sur*uxr[e])) * iv;
  }
  float e0=0, e1=0, e2=0, e3=0, e4=0, e5=0;
#pragma unroll
  for (int e = 0; e < 8; e++) {
    e0 += t1z[e]*t1z[e]; e1 += t1z[e]*bz[e]; e2 += bz[e]*bz[e];
    e3 += t1r[e]*t1r[e]; e4 += t1r[e]*br[e]; e5 += br[e]*br[e];
  }
  e0 = wave_sum(e0); e1 = wave_sum(e1); e2 = wave_sum(e2);
  e3 = wave_sum(e3); e4 = wave_sum(e4); e5 = wave_sum(e5);
  float t2z[8], t2r[8];
  {
    const float iv = 1.f / fmaxf(1.f + 2.f*e1 + e0*e2, EPSF);
    const float c1 = 1.f + 2.f*e1 + e2, c2 = 1.f - e0;
#pragma unroll
    for (int e = 0; e < 8; e++) t2z[e] = (c1*t1z[e] + c2*bz[e]) * iv;
  }
  {
    const float iv = 1.f / fmaxf(1.f + 2.f*e4 + e3*e5, EPSF);
    const float c1 = 1.f + 2.f*e4 + e5, c2 = 1.f - e3;
#pragma unroll
    for (int e = 0; e < 8; e++) t2r[e] = (c1*t1r[e] + c2*br[e]) * iv;
  }
  float n0 = 0, n1 = 0;
#pragma unroll
  for (int e = 0; e < 8; e++) { n0 += t2z[e]*t2z[e]; n1 += t2r[e]*t2r[e]; }
  n0 = wave_sum(n0); n1 = wave_sum(n1);
  const float nz = sqrtf(fmaxf(n0, EPSF)); const float fz = artanh_c(nz) / nz;
  const float nr = sqrtf(fmaxf(n1, EPSF)); const float frg = artanh_c(nr) / nr;
  float wx[8];
  float rw = 0;
#pragma unroll
  for (int e = 0; e < 8; e++) {
    pz[e] = sigmoidf(fz * t2z[e]);
    const float rr = sigmoidf(frg * t2r[e]);
    wx[e] = rr * h[e];
    rw += wx[e]*wx[e];
  }
  rw = wave_sum(rw);
  const float wxn = sqrtf(fmaxf(rw, EPSF));
  const float trh = tanhf(wxn / xn_h * axn_h);
  const float srh = (wxn <= 1e-7f) ? 0.f : trh / wxn;
  const float xn_rh = (wxn <= 1e-7f) ? sqrtf(EPSF) : fmaxf(trh, sqrtf(EPSF));
#pragma unroll
  for (int e = 0; e < 8; e++) { rh[e] = srh * wx[e]; puhx[e] = suh * uxh[e]; }
  o_xnrh = xn_rh; o_axnrh = artanh_c(xn_rh); o_y2u = y2u; o_sh2 = sh2;
}

// ---------- row-local update math ----------
__device__ __forceinline__ void update_row(
    const float mt_[8], const float bh[8],
    const float pz[8], const float puhx[8], const float phv[8],
    float p_xnrh, float p_axnrh, float p_y2u, float p_sh2,
    float hnew[8])
{
  float a0s = 0, a1s = 0;
#pragma unroll
  for (int e = 0; e < 8; e++) { a0s += mt_[e]*mt_[e]; a1s += mt_[e]*puhx[e]; }
  a0s = wave_sum(a0s); a1s = wave_sum(a1s);
  const float m = sqrtf(fmaxf(a0s, EPSF));
  const float tt = tanhf(m / p_xnrh * p_axnrh);
  const float st = (m <= 1e-7f) ? 0.f : tt/m;
  const float x2 = (m <= 1e-7f) ? 0.f : tt*tt;
  float t1[8];
  {
    const float xy = st * a1s;
    const float iv = 1.f / fmaxf(1.f + 2.f*xy + x2*p_y2u, EPSF);
    const float c1 = 1.f + 2.f*xy + p_y2u, c2 = 1.f - x2;
#pragma unroll
    for (int e = 0; e < 8; e++) t1[e] = (c1*(st*mt_[e]) + c2*puhx[e]) * iv;
  }
  float b0s = 0, b1s = 0, b2s = 0;
#pragma unroll
  for (int e = 0; e < 8; e++) { b0s += t1[e]*t1[e]; b1s += t1[e]*bh[e]; b2s += bh[e]*bh[e]; }
  b0s = wave_sum(b0s); b1s = wave_sum(b1s); b2s = wave_sum(b2s);
  float ht[8];
  {
    const float iv = 1.f / fmaxf(1.f + 2.f*b1s + b0s*b2s, EPSF);
    const float c1 = 1.f + 2.f*b1s + b2s, c2 = 1.f - b0s;
#pragma unroll
    for (int e = 0; e < 8; e++) ht[e] = (c1*t1[e] + c2*bh[e]) * iv;
  }
  float c0s = 0, c1s = 0;
#pragma unroll
  for (int e = 0; e < 8; e++) { c0s += ht[e]*ht[e]; c1s += phv[e]*ht[e]; }
  c0s = wave_sum(c0s); c1s = wave_sum(c1s);
  float delta[8];
  {
    const float xy = -c1s;
    const float iv = 1.f / fmaxf(1.f + 2.f*xy + p_sh2*c0s, EPSF);
    const float c1 = 1.f + 2.f*xy + c0s, c2 = 1.f - p_sh2;
#pragma unroll
    for (int e = 0; e < 8; e++) delta[e] = (c1*(-phv[e]) + c2*ht[e]) * iv;
  }
  float d0s = 0, d1s = 0, d2s = 0;
#pragma unroll
  for (int e = 0; e < 8; e++) {
    const float ww = pz[e]*delta[e];
    d0s += delta[e]*delta[e]; d1s += ww*ww; d2s += phv[e]*ww;
  }
  d0s = wave_sum(d0s); d1s = wave_sum(d1s); d2s = wave_sum(d2s);
  const float dn = sqrtf(fmaxf(d0s, EPSF));
  const float axnd = artanh_c(dn);
  const float wxn = sqrtf(fmaxf(d1s, EPSF));
  const float tzd = tanhf(wxn / dn * axnd);
  const float szd = (wxn <= 1e-7f) ? 0.f : tzd/wxn;
  const float y2zd = (wxn <= 1e-7f) ? 0.f : tzd*tzd;
  const float xy = szd * d2s;
  const float iv = 1.f / fmaxf(1.f + 2.f*xy + p_sh2*y2zd, EPSF);
  const float c1 = 1.f + 2.f*xy + y2zd, c2 = 1.f - p_sh2;
#pragma unroll
  for (int e = 0; e < 8; e++) hnew[e] = (c1*phv[e] + c2*(szd*pz[e]*delta[e])) * iv;
}

// ---------- row-local RNN: 128 blocks x 256 threads x 8 rows ----------
// r8: small blocks (4 waves) -> VGPR budget up to 512 -> 16KB bursts/wave in flight.
// A-frag lanes fr>=8 read duplicate rows (fr&7): MFMA rows independent, outputs
// masked at store (kg<2). LDS (57.6KB): H_hi@0 H_lo@8K (8x1KB rows),
// x_hi@16K x_lo@20K (8x512B), rh_hi@24K rh_lo@32K (8x1KB), htm f32[8][520]@40960.
// XOR swizzle byte^=((row&7)<<4) on H/x/rh planes. y global bf16 [8][2560]/block.
__global__ __launch_bounds__(256, 1) void k_rnn(
    const float* __restrict__ emb, const int* __restrict__ src_t,
    const int* __restrict__ tgt_t, const float* __restrict__ b_src,
    const float* __restrict__ b_tgt,
    const bf16* __restrict__ W0h_, const bf16* __restrict__ W1h_,
    ushort* __restrict__ yws, float* __restrict__ hbuf)
{
  const int bid = blockIdx.x, tid = threadIdx.x;
  const int w = tid >> 6, lane = tid & 63;          // w in 0..3
  const int fr = lane & 15, kg = lane >> 4;
  const int fr7 = fr & 7;
  const int g = (bid & 7) >> 2;                     // GRU by XCD half (round-robin map)
  const int b8 = (bid & 3) * 16 + (bid >> 3);       // 0..63 within GRU
  const bf16* W0h = W0h_ + (size_t)g * 917504;
  const bf16* W1h = W1h_ + (size_t)g * 262144;
  const int* toks = g ? tgt_t : src_t;
  const float* bb = g ? b_tgt : b_src;
  ushort* yg = yws + (size_t)bid * 20480;           // [8][2560] bf16 block-private

  __shared__ char L[57600];
  float* htmL = (float*)(L + 40960);                // [8][520] f32
  for (int i = tid; i < 1024; i += 256) ((float4*)L)[i] = make_float4(0.f,0.f,0.f,0.f);

  float p_xnx[2], p_axnx[2];
  float pz_[2][8], puhx_[2][8], phh_[2][8];
  float p_xnrh[2], p_axnrh[2], p_y2u[2], p_sh2[2];

#define XLOAD(RI, TOKIDX)                                                        \
  {                                                                              \
    const int row = w*2 + (RI);                                                  \
    const int tok = toks[(b8*8 + row)*100 + (TOKIDX)];                           \
    const float4 ev = ((const float4*)(emb + (size_t)tok * 256))[lane];          \
    float ss = ev.x*ev.x + ev.y*ev.y + ev.z*ev.z + ev.w*ev.w;                    \
    ss = wave_sum(ss);                                                           \
    const float un = sqrtf(fmaxf(ss, EPSF));                                     \
    const float fac = tanhf(un) / un;                                            \
    const float xnv = sqrtf(fmaxf(fac*fac*ss, EPSF));                            \
    p_xnx[RI] = xnv; p_axnx[RI] = artanh_c(xnv);                                 \
    ushort th[4], tl[4];                                                         \
    split2(fac*ev.x, th[0], tl[0]); split2(fac*ev.y, th[1], tl[1]);              \
    split2(fac*ev.z, th[2], tl[2]); split2(fac*ev.w, th[3], tl[3]);              \
    const unsigned xo = (unsigned)((row*512 + lane*8) ^ ((row & 7) << 4));       \
    *(ushort4*)(L + 16384 + xo) = make_ushort4(th[0],th[1],th[2],th[3]);         \
    *(ushort4*)(L + 20480 + xo) = make_ushort4(tl[0],tl[1],tl[2],tl[3]);         \
  }

  XLOAD(0, 0)
  XLOAD(1, 0)
  __syncthreads();

  for (int s = 0; s < 100; s++) {
    // ===== phase 1a: y[:, 0:1024] = H @ {Whz|Whr}^T (K=512, 16 tiles/wave) =====
    {
      const f32x4 z4 = {0.f,0.f,0.f,0.f};
      f32x4 acc[16];
#pragma unroll
      for (int t = 0; t < 16; t++) acc[t] = z4;
      for (int ki = 0; ki < 16; ki++) {
        short8 bfr[16];
#pragma unroll
        for (int t = 0; t < 16; t++)
          bfr[t] = *(const short8*)(W0h + (size_t)(((w*16 + t)*16 + ki)*512) + lane*8);
        const unsigned ao = (unsigned)((fr7*1024 + ki*64 + kg*16) ^ (fr7 << 4));
        const short8 aHi = *(const short8*)(L + ao);
        const short8 aLo = *(const short8*)(L + 8192 + ao);
#pragma unroll
        for (int t = 0; t < 16; t++) {
          acc[t] = __builtin_amdgcn_mfma_f32_16x16x32_bf16(aHi, bfr[t], acc[t], 0,0,0);
          acc[t] = __builtin_amdgcn_mfma_f32_16x16x32_bf16(aLo, bfr[t], acc[t], 0,0,0);
        }
      }
      if (kg < 2) {
#pragma unroll
        for (int t = 0; t < 16; t++) {
          const int colb = (w*16 + t)*16 + fr;
#pragma unroll
          for (int r = 0; r < 4; r++)
            yg[(size_t)(kg*4 + r)*2560 + colb] = f2bu(acc[t][r]);
        }
      }
    }
    // ===== phase 1b: y[:, 1024:2560] = X @ {Uxz|Uxr|Uxh}^T (K=256, 2x12 tiles/wave) =====
#pragma unroll
    for (int p = 0; p < 2; p++) {
      const f32x4 z4 = {0.f,0.f,0.f,0.f};
      f32x4 acc[12];
#pragma unroll
      for (int t = 0; t < 12; t++) acc[t] = z4;
      for (int ki = 0; ki < 8; ki++) {
        short8 bfr[12];
#pragma unroll
        for (int t = 0; t < 12; t++)
          bfr[t] = *(const short8*)(W0h + 524288 +
                      (size_t)(((w*24 + p*12 + t)*8 + ki)*512) + lane*8);
        const unsigned ao = (unsigned)((fr7*512 + ki*64 + kg*16) ^ (fr7 << 4));
        const short8 aHi = *(const short8*)(L + 16384 + ao);
        const short8 aLo = *(const short8*)(L + 20480 + ao);
#pragma unroll
        for (int t = 0; t < 12; t++) {
          acc[t] = __builtin_amdgcn_mfma_f32_16x16x32_bf16(aHi, bfr[t], acc[t], 0,0,0);
          acc[t] = __builtin_amdgcn_mfma_f32_16x16x32_bf16(aLo, bfr[t], acc[t], 0,0,0);
        }
      }
      if (kg < 2) {
#pragma unroll
        for (int t = 0; t < 12; t++) {
          const int colb = 1024 + (w*24 + p*12 + t)*16 + fr;
#pragma unroll
          for (int r = 0; r < 4; r++)
            yg[(size_t)(kg*4 + r)*2560 + colb] = f2bu(acc[t][r]);
        }
      }
    }
    __syncthreads();

    // ===== phase 2: gates, wave handles rows w*2, w*2+1 =====
#define PH2_ROW(RI)                                                              \
    {                                                                            \
      const int row = w*2 + (RI);                                                \
      const ushort* growu = yg + (size_t)row * 2560;                             \
      float h[8], whz[8], whr[8], uxz[8], uxr[8], uxh[8], bz[8], br[8];          \
      _Pragma("unroll")                                                          \
      for (int q = 0; q < 2; q++) {                                              \
        const int j4 = lane + 64*q;                                              \
        const unsigned ho = (unsigned)((row*1024 + j4*8) ^ ((row & 7) << 4));    \
        const ushort4 hh4 = *(const ushort4*)(L + ho);                           \
        const ushort4 hl4 = *(const ushort4*)(L + 8192 + ho);                    \
        const ushort4 vz  = ((const ushort4*)growu)[j4];                         \
        const ushort4 vr  = ((const ushort4*)(growu + 512))[j4];                 \
        const ushort4 uz  = ((const ushort4*)(growu + 1024))[j4];                \
        const ushort4 ur  = ((const ushort4*)(growu + 1536))[j4];                \
        const ushort4 uh  = ((const ushort4*)(growu + 2048))[j4];                \
        const float4 vbz = ((const float4*)(bb + 1024))[j4];                     \
        const float4 vbr = ((const float4*)bb)[j4];                              \
        _Pragma("unroll")                                                        \
        for (int i = 0; i < 4; i++) {                                            \
          const int e = q*4 + i;                                                 \
          h[e] = bu2f(U4E(hh4,i)) + bu2f(U4E(hl4,i));                            \
          whz[e] = bu2f(U4E(vz,i)); whr[e] = bu2f(U4E(vr,i));                    \
          uxz[e] = bu2f(U4E(uz,i)); uxr[e] = bu2f(U4E(ur,i));                    \
          uxh[e] = bu2f(U4E(uh,i));                                              \
          bz[e] = F4E(vbz,i); br[e] = F4E(vbr,i);                               \
        }                                                                        \
      }                                                                          \
      float rh[8];                                                               \
      gate_row(h, whz, whr, uxz, uxr, uxh, bz, br, p_xnx[RI], p_axnx[RI],        \
               rh, pz_[RI], puhx_[RI],                                           \
               p_xnrh[RI], p_axnrh[RI], p_y2u[RI], p_sh2[RI]);                   \
      _Pragma("unroll")                                                          \
      for (int e = 0; e < 8; e++) phh_[RI][e] = h[e];                            \
      _Pragma("unroll")                                                          \
      for (int q = 0; q < 2; q++) {                                              \
        const int j4 = lane + 64*q;                                              \
        const unsigned ro = (unsigned)((row*1024 + j4*8) ^ ((row & 7) << 4));    \
        ushort th[4], tl[4];                                                     \
        _Pragma("unroll")                                                        \
        for (int i = 0; i < 4; i++) split2(rh[q*4+i], th[i], tl[i]);             \
        *(ushort4*)(L + 24576 + ro) = make_ushort4(th[0],th[1],th[2],th[3]);     \
        *(ushort4*)(L + 32768 + ro) = make_ushort4(tl[0],tl[1],tl[2],tl[3]);     \
      }                                                                          \
    }

    PH2_ROW(0)
    PH2_ROW(1)
    __syncthreads();

    // ===== phase 3: htm = RH @ W1^T (K=512, 8 tiles/wave) -> LDS =====
    {
      const f32x4 z4 = {0.f,0.f,0.f,0.f};
      f32x4 acc[8];
#pragma unroll
      for (int t = 0; t < 8; t++) acc[t] = z4;
      for (int ki = 0; ki < 16; ki++) {
        short8 bfr[8];
#pragma unroll
        for (int t = 0; t < 8; t++)
          bfr[t] = *(const short8*)(W1h + (size_t)(((w*8 + t)*16 + ki)*512) + lane*8);
        const unsigned ao = (unsigned)((fr7*1024 + ki*64 + kg*16) ^ (fr7 << 4));
        const short8 aHi = *(const short8*)(L + 24576 + ao);
        const short8 aLo = *(const short8*)(L + 32768 + ao);
#pragma unroll
        for (int t = 0; t < 8; t++) {
          acc[t] = __builtin_amdgcn_mfma_f32_16x16x32_bf16(aHi, bfr[t], acc[t], 0,0,0);
          acc[t] = __builtin_amdgcn_mfma_f32_16x16x32_bf16(aLo, bfr[t], acc[t], 0,0,0);
        }
      }
      if (kg < 2) {
#pragma unroll
        for (int t = 0; t < 8; t++) {
          const int colb = (w*8 + t)*16 + fr;
#pragma unroll
          for (int r = 0; r < 4; r++)
            htmL[(kg*4 + r)*520 + colb] = acc[t][r];
        }
      }
    }
    __syncthreads();

    // ===== phase 4: update, wave handles rows w*2, w*2+1; prefetch next x =====
#define PH4_ROW(RI)                                                              \
    {                                                                            \
      const int row = w*2 + (RI);                                                \
      float mt_[8], bh[8];                                                       \
      _Pragma("unroll")                                                          \
      for (int q = 0; q < 2; q++) {                                              \
        const int j4 = lane + 64*q;                                              \
        const float4 vm = ((const float4*)(htmL + row*520))[j4];                 \
        const float4 vb = ((const float4*)(bb + 512))[j4];                       \
        _Pragma("unroll")                                                        \
        for (int i = 0; i < 4; i++) {                                            \
          mt_[q*4+i] = F4E(vm,i); bh[q*4+i] = F4E(vb,i);                         \
        }                                                                        \
      }                                                                          \
      float hnew[8];                                                             \
      update_row(mt_, bh, pz_[RI], puhx_[RI], phh_[RI],                          \
                 p_xnrh[RI], p_axnrh[RI], p_y2u[RI], p_sh2[RI], hnew);           \
      _Pragma("unroll")                                                          \
      for (int q = 0; q < 2; q++) {                                              \
        const int j4 = lane + 64*q;                                              \
        const unsigned ho = (unsigned)((row*1024 + j4*8) ^ ((row & 7) << 4));    \
        ushort th[4], tl[4];                                                     \
        _Pragma("unroll")                                                        \
        for (int i = 0; i < 4; i++) split2(hnew[q*4+i], th[i], tl[i]);           \
        *(ushort4*)(L + ho) = make_ushort4(th[0],th[1],th[2],th[3]);             \
        *(ushort4*)(L + 8192 + ho) = make_ushort4(tl[0],tl[1],tl[2],tl[3]);      \
        if (s == 99)                                                             \
          ((float4*)(hbuf + (size_t)(g*512 + b8*8 + row)*512))[j4] =             \
              make_float4(hnew[q*4], hnew[q*4+1], hnew[q*4+2], hnew[q*4+3]);     \
      }                                                                          \
      if (s + 1 < 100) XLOAD(RI, s + 1)                                          \
    }

    PH4_ROW(0)
    PH4_ROW(1)
    __syncthreads();
  }
}

// ---------- head projection GEMM (f32, runs once; verified rounds 2-7) ----------
__global__ __launch_bounds__(256) void gemm_k(
    const float* __restrict__ hbuf,
    const float* __restrict__ wp_src, const float* __restrict__ wp_tgt,
    const int* __restrict__ alignment,
    float* __restrict__ out)
{
  const int rt = blockIdx.x, ct = blockIdx.y;
  const int rowBase = rt * 64;
  const int tid = threadIdx.x;
  const int chunk = ct >> 2;
  const int colBase = ct * 64, ldo = 512, kdim = 512;
  const float* W = (chunk ? wp_tgt : wp_src) + (size_t)((ct & 3) * 64) * 512;
  const int ar = tid >> 2, ak = (tid & 3) * 4;
  int arow = rowBase + ar;
  if (chunk) arow = 512 + alignment[arow];
  const float* Arow = hbuf + (size_t)arow * kdim;
  const float* Wrow = W + (size_t)(tid >> 2) * kdim + (tid & 3) * 4;

  __shared__ __align__(16) float As[16][68];
  __shared__ __align__(16) float Bs[16][68];
  float acc[4][4] = {{0.f}};
  const int ty = tid >> 4, tx = tid & 15;

  for (int k0 = 0; k0 < kdim; k0 += 16) {
    const float4 av = *(const float4*)(Arow + k0 + ak);
    const float4 bv = *(const float4*)(Wrow + k0);
    const int bj = tid >> 2;
    As[ak + 0][ar] = av.x; As[ak + 1][ar] = av.y; As[ak + 2][ar] = av.z; As[ak + 3][ar] = av.w;
    Bs[ak + 0][bj] = bv.x; Bs[ak + 1][bj] = bv.y; Bs[ak + 2][bj] = bv.z; Bs[ak + 3][bj] = bv.w;
    __syncthreads();
#pragma unroll
    for (int kk = 0; kk < 16; kk++) {
      const float4 a4 = *(const float4*)(&As[kk][ty * 4]);
      const float4 b4 = *(const float4*)(&Bs[kk][tx * 4]);
      acc[0][0] += a4.x * b4.x; acc[0][1] += a4.x * b4.y; acc[0][2] += a4.x * b4.z; acc[0][3] += a4.x * b4.w;
      acc[1][0] += a4.y * b4.x; acc[1][1] += a4.y * b4.y; acc[1][2] += a4.y * b4.z; acc[1][3] += a4.y * b4.w;
      acc[2][0] += a4.z * b4.x; acc[2][1] += a4.z * b4.y; acc[2][2] += a4.z * b4.z; acc[2][3] += a4.z * b4.w;
      acc[3][0] += a4.w * b4.x; acc[3][1] += a4.w * b4.y; acc[3][2] += a4.w * b4.z; acc[3][3] += a4.w * b4.w;
    }
    __syncthreads();
  }
#pragma unroll
  for (int r = 0; r < 4; r++) {
    float4 o; o.x = acc[r][0]; o.y = acc[r][1]; o.z = acc[r][2]; o.w = acc[r][3];
    *(float4*)(out + (size_t)(rowBase + ty * 4 + r) * ldo + colBase + tx * 4) = o;
  }
}

// ---------- head ----------
template<int N>
__device__ __forceinline__ void block_reduce(float* v) {
  __shared__ float s[4][N];
  __syncthreads();
  const int lane = threadIdx.x & 63;
  const int wv = threadIdx.x >> 6;
#pragma unroll
  for (int n = 0; n < N; n++) {
    float x = v[n];
#pragma unroll
    for (int o = 32; o > 0; o >>= 1) x += __shfl_down(x, o);
    if (lane == 0) s[wv][n] = x;
  }
  __syncthreads();
#pragma unroll
  for (int n = 0; n < N; n++) v[n] = s[0][n] + s[1][n] + s[2][n] + s[3][n];
}

__global__ __launch_bounds__(256) void k_head(
    const float* __restrict__ hb, const float* __restrict__ mxb,
    const float* __restrict__ bp_src, const float* __restrict__ bp_tgt,
    const float* __restrict__ dist_bias, const float* __restrict__ plane_p,
    const float* __restrict__ plane_a, const int* __restrict__ alignment,
    float* __restrict__ outp)
{
  const int b = blockIdx.x;
  const int t = threadIdx.x;
  const int arow = 512 + alignment[b];
  float hs[2], htg[2];
  hs[0] = hb[(size_t)b * 512 + t];      hs[1] = hb[(size_t)b * 512 + 256 + t];
  htg[0] = hb[(size_t)arow * 512 + t];  htg[1] = hb[(size_t)arow * 512 + 256 + t];
  const float mxs = mxb[(size_t)b * 512 + t];
  const float mxt = mxb[(size_t)b * 512 + 256 + t];
  const float bps = bp_src[t], bpt = bp_tgt[t], db = dist_bias[t];
  const float pp0 = plane_p[t], pp1 = plane_p[256 + t];
  const float pa0 = plane_a[t], pa1 = plane_a[256 + t];

  float rA[5] = {0, 0, 0, 0, 0};
#pragma unroll
  for (int e = 0; e < 2; e++) {
    rA[0] += hs[e] * hs[e]; rA[1] += htg[e] * htg[e]; rA[2] += hs[e] * htg[e];
  }
  rA[3] = mxs * mxs; rA[4] = mxt * mxt;
  block_reduce<5>(rA);
  const float shs = rA[0], sht = rA[1], dot_st = rA[2];
  const float xns = sqrtf(fmaxf(shs, EPSF)), axns = artanh_c(xns);
  const float xnt = sqrtf(fmaxf(sht, EPSF)), axnt = artanh_c(xnt);
  const float ms = sqrtf(fmaxf(rA[3], EPSF)); const float ts = tanhf(ms / xns * axns);
  const float ss = (ms <= 1e-7f) ? 0.f : ts / ms; const float x2s = (ms <= 1e-7f) ? 0.f : ts * ts;
  const float mt = sqrtf(fmaxf(rA[4], EPSF)); const float tt = tanhf(mt / xnt * axnt);
  const float st = (mt <= 1e-7f) ? 0.f : tt / mt; const float x2t = (mt <= 1e-7f) ? 0.f : tt * tt;
  const float vs = ss * mxs, vt = st * mxt;

  float rB[5] = {bps * bps, vs * bps, bpt * bpt, vt * bpt, db * db};
  block_reduce<5>(rB);
  float ps, pt;
  {
    const float y2 = rB[0], xy = rB[1];
    const float iv = 1.f / fmaxf(1.f + 2.f * xy + x2s * y2, EPSF);
    ps = ((1.f + 2.f * xy + y2) * vs + (1.f - x2s) * bps) * iv;
  }
  {
    const float y2 = rB[2], xy = rB[3];
    const float iv = 1.f / fmaxf(1.f + 2.f * xy + x2t * y2, EPSF);
    pt = ((1.f + 2.f * xy + y2) * vt + (1.f - x2t) * bpt) * iv;
  }
  float rC[2] = {ps * ps, pt * pt};
  block_reduce<2>(rC);
  {
    const float n = sqrtf(fmaxf(rC[0], EPSF));
    if (n > 0.999f) ps *= 0.999f / n;
  }
  {
    const float n = sqrtf(fmaxf(rC[1], EPSF));
    if (n > 0.999f) pt *= 0.999f / n;
  }
  float df[2];
  {
    const float xy = -dot_st;
    const float iv = 1.f / fmaxf(1.f + 2.f * xy + shs * sht, EPSF);
    const float c1 = 1.f + 2.f * xy + sht, c2 = 1.f - shs;
#pragma unroll
    for (int e = 0; e < 2; e++) df[e] = (c1 * (-hs[e]) + c2 * htg[e]) * iv;
  }
  float rD[4] = {ps * ps, pt * pt, ps * pt, df[0] * df[0] + df[1] * df[1]};
  block_reduce<4>(rD);
  float pr;
  {
    const float x2 = rD[0], y2 = rD[1], xy = rD[2];
    const float iv = 1.f / fmaxf(1.f + 2.f * xy + x2 * y2, EPSF);
    pr = ((1.f + 2.f * xy + y2) * ps + (1.f - x2) * pt) * iv;
  }
  const float dn = sqrtf(fmaxf(rD[3], EPSF));
  const float dist = 2.f * artanh_c(dn);
  const float d2v = dist * dist;
  const float dbn = sqrtf(fmaxf(rB[4], EPSF));
  const float biasv = tanhf(d2v * artanh_c(dbn)) * db / dbn;

  float rE[3] = {pr * pr, biasv * biasv, pr * biasv};
  block_reduce<3>(rE);
  float pr2;
  {
    const float x2 = rE[0], y2 = rE[1], xy = rE[2];
    const float iv = 1.f / fmaxf(1.f + 2.f * xy + x2 * y2, EPSF);
    pr2 = ((1.f + 2.f * xy + y2) * pr + (1.f - x2) * biasv) * iv;
  }
  float rF[5] = {pp0 * pp0, pp0 * pr2, pp1 * pp1, pp1 * pr2, pr2 * pr2};
  block_reduce<5>(rF);
  float d0, d1;
  {
    const float x2 = rF[0], xy = -rF[1], y2 = rF[4];
    const float iv = 1.f / fmaxf(1.f + 2.f * xy + x2 * y2, EPSF);
    d0 = ((1.f + 2.f * xy + y2) * (-pp0) + (1.f - x2) * pr2) * iv;
  }
  {
    const float x2 = rF[2], xy = -rF[3], y2 = rF[4];
    const float iv = 1.f / fmaxf(1.f + 2.f * xy + x2 * y2, EPSF);
    d1 = ((1.f + 2.f * xy + y2) * (-pp1) + (1.f - x2) * pr2) * iv;
  }
  float rG[6] = {d0 * d0, d0 * pa0, pa0 * pa0, d1 * d1, d1 * pa1, pa1 * pa1};
  block_reduce<6>(rG);
  if (t == 0) {
    const float an0 = sqrtf(fmaxf(rG[2], EPSF));
    const float an1 = sqrtf(fmaxf(rG[5], EPSF));
    outp[b * 2 + 0] = asinhf(2.f * rG[1] / fmaxf((1.f - rG[0]) * an0, EPSF));
    outp[b * 2 + 1] = asinhf(2.f * rG[4] / fmaxf((1.f - rG[3]) * an1, EPSF));
  }
}

// ---------- launch ----------
extern "C" void kernel_launch(void* const* d_in, const int* in_sizes, int n_in,
                              void* d_out, int out_size, void* d_ws, size_t ws_size,
                              hipStream_t stream) {
  const float* emb       = (const float*)d_in[0];
  const float* w_ih_src  = (const float*)d_in[1];
  const float* w_hh_src  = (const float*)d_in[2];
  const float* b_src     = (const float*)d_in[3];
  const float* w_ih_tgt  = (const float*)d_in[4];
  const float* w_hh_tgt  = (const float*)d_in[5];
  const float* b_tgt     = (const float*)d_in[6];
  const float* wp_src    = (const float*)d_in[7];
  const float* bp_src    = (const float*)d_in[8];
  const float* wp_tgt    = (const float*)d_in[9];
  const float* bp_tgt    = (const float*)d_in[10];
  const float* dist_bias = (const float*)d_in[11];
  const float* plane_p   = (const float*)d_in[12];
  const float* plane_a   = (const float*)d_in[13];
  const int* src_t       = (const int*)d_in[14];
  const int* tgt_t       = (const int*)d_in[15];
  const int* alignment   = (const int*)d_in[16];
  float* outp            = (float*)d_out;

  char* wsb = (char*)d_ws;
  ushort* yws  = (ushort*)(wsb + 0);         // 128 x [8][2560] bf16 = 5.24 MB
  float* hbuf  = (float*)(wsb + 5242880);    // [1024][512] f32 = 2 MB
  float* mxb   = (float*)(wsb + 7340032);    // [512][512]  f32 = 1 MB
  bf16*  W0h   = (bf16*)(wsb + 8388608);     // 1835008 bf16 = 3.67 MB
  bf16*  W1h   = (bf16*)(wsb + 12058624);    // 524288 bf16 = 1.05 MB; end ~13.1 MB

  k_wconv<<<9216, 256, 0, stream>>>(w_ih_src, w_hh_src, w_ih_tgt, w_hh_tgt,
                                    W0h, W1h);
  k_rnn<<<128, 256, 0, stream>>>(emb, src_t, tgt_t, b_src, b_tgt,
                                 W0h, W1h, yws, hbuf);
  gemm_k<<<dim3(8, 8), 256, 0, stream>>>(hbuf, wp_src, wp_tgt, alignment, mxb);
  k_head<<<512, 256, 0, stream>>>(hbuf, mxb, bp_src, bp_tgt, dist_bias,
                                  plane_p, plane_a, alignment, outp);
}